// Round 1
// 325.567 us; speedup vs baseline: 1.0869x; 1.0869x over previous
//
#include <hip/hip_runtime.h>

#define FEAT_C 512
#define Hh 96
#define Ww 96
#define HW (Hh*Ww)
#define NB 8
#define OUTC 409

typedef __attribute__((ext_vector_type(8))) short short8;
typedef __attribute__((ext_vector_type(4))) short short4v;
typedef __attribute__((ext_vector_type(4))) float f32x4;
typedef __fp16 h2 __attribute__((ext_vector_type(2)));
typedef __fp16 h8 __attribute__((ext_vector_type(8)));

__device__ inline ushort f2bf(float x) {
    unsigned u = __float_as_uint(x);
    u += 0x7fffu + ((u >> 16) & 1u);
    return (ushort)(u >> 16);
}

#if __has_builtin(__builtin_amdgcn_fdot2)
__device__ inline float FDOT2(h2 a, h2 b, float c) {
    return __builtin_amdgcn_fdot2(a, b, c, false);
}
#else
__device__ inline float FDOT2(h2 a, h2 b, float c) {
    return c + (float)a[0] * (float)b[0] + (float)a[1] * (float)b[1];
}
#endif

__device__ inline h2 pair(h8 v, int i) {
    switch (i) {
        case 0: return __builtin_shufflevector(v, v, 0, 1);
        case 1: return __builtin_shufflevector(v, v, 2, 3);
        case 2: return __builtin_shufflevector(v, v, 4, 5);
        default: return __builtin_shufflevector(v, v, 6, 7);
    }
}

// ============ kpack: normalize + transpose feature ========================
#define PKPX 32
__global__ __launch_bounds__(256) void kpack(const float* __restrict__ f,
                                             ushort* __restrict__ fnorm) {
    __shared__ ushort tr[PKPX * 512];      // 32 KB
    __shared__ float ssqp[8][PKPX];
    __shared__ float sinvs[PKPX];
    int tid = threadIdx.x;
    int g = tid >> 5, pl = tid & 31;
    int b = blockIdx.y;
    int p0 = blockIdx.x * PKPX;
    const float* fb = f + (size_t)b * FEAT_C * HW + p0 + pl;

    float ssq = 0.f;
#pragma unroll
    for (int q = 0; q < 8; ++q) {
        int u = g * 8 + q;
        float v[8];
#pragma unroll
        for (int j = 0; j < 8; ++j)
            v[j] = fb[(size_t)(u * 8 + j) * HW];
        h2 a0 = __builtin_amdgcn_cvt_pkrtz(v[0], v[1]);
        h2 a1 = __builtin_amdgcn_cvt_pkrtz(v[2], v[3]);
        h2 a2 = __builtin_amdgcn_cvt_pkrtz(v[4], v[5]);
        h2 a3 = __builtin_amdgcn_cvt_pkrtz(v[6], v[7]);
        ssq = FDOT2(a0, a0, ssq); ssq = FDOT2(a1, a1, ssq);
        ssq = FDOT2(a2, a2, ssq); ssq = FDOT2(a3, a3, ssq);
        h8 hv;
        hv[0] = a0[0]; hv[1] = a0[1]; hv[2] = a1[0]; hv[3] = a1[1];
        hv[4] = a2[0]; hv[5] = a2[1]; hv[6] = a3[0]; hv[7] = a3[1];
        int up = u ^ (pl & 7);
        *(h8*)&tr[pl * 512 + up * 8] = hv;
    }
    ssqp[g][pl] = ssq;
    __syncthreads();
    if (tid < PKPX) {
        float s = 0.f;
#pragma unroll
        for (int gg = 0; gg < 8; ++gg) s += ssqp[gg][tid];
        sinvs[tid] = 1.0f / fmaxf(sqrtf(s), 1e-12f);
    }
    __syncthreads();

    size_t ob = ((size_t)b * HW + p0) * 512;
#pragma unroll
    for (int i = 0; i < 8; ++i) {
        int t = tid + i * 256;
        int r = t >> 6, k = t & 63;
        h8 hv = *(const h8*)&tr[r * 512 + ((k ^ (r & 7)) * 8)];
        float s = sinvs[r];
        h2 o0 = __builtin_amdgcn_cvt_pkrtz((float)hv[0] * s, (float)hv[1] * s);
        h2 o1 = __builtin_amdgcn_cvt_pkrtz((float)hv[2] * s, (float)hv[3] * s);
        h2 o2 = __builtin_amdgcn_cvt_pkrtz((float)hv[4] * s, (float)hv[5] * s);
        h2 o3 = __builtin_amdgcn_cvt_pkrtz((float)hv[6] * s, (float)hv[7] * s);
        h8 ov;
        ov[0] = o0[0]; ov[1] = o0[1]; ov[2] = o1[0]; ov[3] = o1[1];
        ov[4] = o2[0]; ov[5] = o2[1]; ov[6] = o3[0]; ov[7] = o3[1];
        *(h8*)&fnorm[ob + (size_t)r * 512 + k * 8] = ov;
    }
}

// ============ kss4: self-similarity from packed normalized f16 ============
#define SS_NT4 576

__global__ __launch_bounds__(256) void kss4(const ushort* __restrict__ fnorm,
                                            float* __restrict__ out) {
    __shared__ ushort tile[2][144 * 32];
    int tid = threadIdx.x;
    int w = tid >> 6, lane = tid & 63;
    int slab = (lane >> 4) & 3, p16 = lane & 15;
    int ox = p16 & 7, oy = 2 * w + (p16 >> 3);
    int x0 = blockIdx.x * 8, y0 = blockIdx.y * 8, b = blockIdx.z;

    const ushort* t_src[3];
    int t_dst[3];
    bool t_ok[3];
#pragma unroll
    for (int k = 0; k < 3; ++k) {
        int task = tid + k * 256;
        t_ok[k] = false; t_src[k] = fnorm; t_dst[k] = 0;
        if (task < SS_NT4) {
            int icg = task & 3, pix = task >> 2;
            int hrow = pix / 12, hcol = pix % 12;
            int gy = y0 + hrow - 2, gx = x0 + hcol - 2;
            t_dst[k] = task * 8;
            if (gy >= 0 && gy < Hh && gx >= 0 && gx < Ww) {
                t_ok[k] = true;
                t_src[k] = fnorm + ((size_t)b * HW + (size_t)gy * Ww + gx) * 512
                         + icg * 8;
            }
        } else {
            t_dst[k] = -1;
        }
    }

    float acc[25];
#pragma unroll
    for (int o = 0; o < 25; ++o) acc[o] = 0.f;

    auto stage = [&](int chunk, int nbuf) {
        short8 v[3];
#pragma unroll
        for (int k = 0; k < 3; ++k) {
            v[k] = (short8)0;
            if (t_ok[k]) v[k] = *(const short8*)(t_src[k] + chunk * 32);
        }
#pragma unroll
        for (int k = 0; k < 3; ++k)
            if (t_dst[k] >= 0)
                *(short8*)&tile[nbuf][t_dst[k]] = v[k];
    };

    int pc = (oy + 2) * 12 + (ox + 2);
    auto compute = [&](int kb) {
        const ushort* tb = &tile[kb][slab * 8];
        h8 ctr = *(const h8*)(tb + pc * 32);
#pragma unroll
        for (int dx = 0; dx < 5; ++dx)
#pragma unroll
            for (int dy = 0; dy < 5; ++dy) {
                int pn = (oy + dy) * 12 + (ox + dx);
                h8 nbv = *(const h8*)(tb + pn * 32);
                float a = acc[dx * 5 + dy];
                a = FDOT2(pair(nbv, 0), pair(ctr, 0), a);
                a = FDOT2(pair(nbv, 1), pair(ctr, 1), a);
                a = FDOT2(pair(nbv, 2), pair(ctr, 2), a);
                a = FDOT2(pair(nbv, 3), pair(ctr, 3), a);
                acc[dx * 5 + dy] = a;
            }
    };

    stage(0, 0);
    __syncthreads();
    for (int c = 0; c < 16; ++c) {
        if (c < 15) stage(c + 1, (c + 1) & 1);
        compute(c & 1);
        __syncthreads();
    }

    size_t ob = (size_t)b * OUTC * HW + (size_t)(y0 + oy) * Ww + (x0 + ox);
#pragma unroll
    for (int dx = 0; dx < 5; ++dx)
#pragma unroll
        for (int dy = 0; dy < 5; ++dy) {
            int o = dx * 5 + dy;
            float v = acc[o];
            v += __shfl_xor(v, 16);
            v += __shfl_xor(v, 32);
            if (slab == 0)
                out[ob + (size_t)o * HW] = v;
        }
}

// ============ weight repacks ==============================================
__global__ __launch_bounds__(256) void kwpack0(const float* __restrict__ w0,
                                               ushort* __restrict__ wpk0) {
    int i = blockIdx.x * 256 + threadIdx.x;
    if (i >= 9 * 256 * 32) return;
    int ic = i & 31, oc = (i >> 5) & 255, t = i >> 13;
    wpk0[i] = (ic < 25) ? f2bf(w0[(size_t)oc * 225 + ic * 9 + t]) : (ushort)0;
}

// w1 [128][256][3][3] f32 -> wpk1 [9][8 chunk][128 oc][32 ic] bf16
__global__ __launch_bounds__(256) void kwpack1(const float* __restrict__ w1,
                                               ushort* __restrict__ wpk1) {
    int i = blockIdx.x * 256 + threadIdx.x;
    if (i >= 9 * 8 * 128 * 32) return;
    int icc = i & 31, oc = (i >> 5) & 127, c = (i >> 12) & 7, t = i >> 15;
    int ic = c * 32 + icc;
    wpk1[i] = f2bf(w1[((size_t)oc * 256 + ic) * 9 + t]);
}

// ============ kconv1m: 25->256 conv via MFMA ==============================
#define C1PAD 40
__global__ __launch_bounds__(256) void kconv1m(const float* __restrict__ ssin,
                                               const ushort* __restrict__ wpk0,
                                               const float* __restrict__ b0,
                                               float* __restrict__ outp,
                                               ushort* __restrict__ sspk) {
    __shared__ ushort wtile[100][C1PAD];
    int tid = threadIdx.x;
    int lane = tid & 63, wM = tid >> 6;
    int l15 = lane & 15, l4 = lane >> 4;
    int x0 = blockIdx.x * 8, y0 = blockIdx.y * 8, b = blockIdx.z;

    const float* sb = ssin + (size_t)b * OUTC * HW;
    if (tid < 100) {
        int py = tid / 10, px = tid % 10;
        int gy = y0 + py - 1, gx = x0 + px - 1;
        ushort row[32];
        bool ok = (gy >= 0 && gy < Hh && gx >= 0 && gx < Ww);
        int gyx = ok ? gy * Ww + gx : 0;
#pragma unroll
        for (int o = 0; o < 25; ++o)
            row[o] = ok ? f2bf(sb[(size_t)o * HW + gyx]) : (ushort)0;
#pragma unroll
        for (int o = 25; o < 32; ++o) row[o] = 0;
#pragma unroll
        for (int q = 0; q < 4; ++q)
            *(short8*)&wtile[tid][q * 8] = *(short8*)&row[q * 8];
    }
    __syncthreads();

    f32x4 acc[4][4];
#pragma unroll
    for (int mi = 0; mi < 4; ++mi)
#pragma unroll
        for (int ni = 0; ni < 4; ++ni)
            acc[mi][ni] = (f32x4)0.f;

#pragma unroll
    for (int t = 0; t < 9; ++t) {
        int ky = t / 3, kx = t % 3;
        short8 a[4], bv[4];
#pragma unroll
        for (int mi = 0; mi < 4; ++mi)
            a[mi] = *(const short8*)(wpk0 +
                    ((size_t)(t * 256 + wM * 64 + mi * 16 + l15)) * 32 + l4 * 8);
#pragma unroll
        for (int ni = 0; ni < 4; ++ni) {
            int px_id = ni * 16 + l15;
            int pn = (px_id / 8 + ky) * 10 + (px_id & 7) + kx;
            bv[ni] = *(const short8*)&wtile[pn][l4 * 8];
        }
#pragma unroll
        for (int mi = 0; mi < 4; ++mi)
#pragma unroll
            for (int ni = 0; ni < 4; ++ni)
                acc[mi][ni] = __builtin_amdgcn_mfma_f32_16x16x32_bf16(
                    a[mi], bv[ni], acc[mi][ni], 0, 0, 0);
    }

    size_t ob = (size_t)b * OUTC * HW + (size_t)25 * HW;
    size_t pb = (size_t)b * HW;
#pragma unroll
    for (int mi = 0; mi < 4; ++mi)
#pragma unroll
        for (int ni = 0; ni < 4; ++ni) {
            int px_id = ni * 16 + l15;
            int gy = y0 + (px_id >> 3), gx = x0 + (px_id & 8 - 1 + 1 - 1);
            gx = x0 + (px_id & 7);
            int oc_b = wM * 64 + mi * 16 + l4 * 4;
            short4v hv;
#pragma unroll
            for (int r = 0; r < 4; ++r) {
                float v = fmaxf(acc[mi][ni][r] + b0[oc_b + r], 0.f);
                outp[ob + (size_t)(oc_b + r) * HW + (size_t)gy * Ww + gx] = v;
                hv[r] = (short)f2bf(v);
            }
            *(short4v*)&sspk[(pb + (size_t)gy * Ww + gx) * 256 + oc_b] = hv;
        }
}

// ============ kconv2n: 256->128 conv via MFMA, 16x8 tile ==================
// grid (6,12,NB); 4 waves: wM = oc-half (64 oc), wN = row-half (4 rows x 16
// cols = 64 px). acc[4][4] => 16 MFMA per tap from 4 global weight loads +
// 4 LDS reads (2x arithmetic per load vs previous 8x8 tile), and half the
// per-dispatch weight re-reads (576 blocks x 589KB). Halo 10x18 px.
// LDS unit swizzle u^((px>>1)&3) kept: both ds_write_b128 and ds_read_b128
// conflict-free.
#define NPX2 180
__global__ __launch_bounds__(256, 3) void kconv2n(const ushort* __restrict__ sspk,
                                                  const ushort* __restrict__ wpk,
                                                  const float* __restrict__ b1,
                                                  float* __restrict__ outp) {
    __shared__ ushort lds[2][NPX2 * 32];   // 2 x 11.52 KB
    int tid = threadIdx.x;
    int lane = tid & 63, wid = tid >> 6;
    int wM = wid >> 1, wN = wid & 1;
    int l15 = lane & 15, l4 = lane >> 4;
    int x0 = blockIdx.x * 16, y0 = blockIdx.y * 8, b = blockIdx.z;

    f32x4 acc[4][4];
#pragma unroll
    for (int mi = 0; mi < 4; ++mi)
#pragma unroll
        for (int ni = 0; ni < 4; ++ni)
            acc[mi][ni] = (f32x4)0.f;

    // staging: 720 16B-units per chunk (180 px x 4 units), 3 tasks/thread
    size_t t_src[3];
    int t_dst[3];
    bool t_ok[3];
#pragma unroll
    for (int k = 0; k < 3; ++k) {
        int task = tid + k * 256;
        t_ok[k] = false; t_src[k] = 0; t_dst[k] = -1;
        if (task < 720) {
            int px = task >> 2, u = task & 3;
            int iy = px / 18, ix = px % 18;
            int gy = y0 + iy - 1, gx = x0 + ix - 1;
            t_dst[k] = px * 32 + (u ^ ((px >> 1) & 3)) * 8;
            if (gy >= 0 && gy < Hh && gx >= 0 && gx < Ww) {
                t_ok[k] = true;
                t_src[k] = ((size_t)b * HW + (size_t)gy * Ww + gx) * 256 + u * 8;
            }
        }
    }

    auto stage_load = [&](int c, short8* v) {
#pragma unroll
        for (int k = 0; k < 3; ++k) {
            v[k] = (short8)0;
            if (t_ok[k])
                v[k] = *(const short8*)(sspk + t_src[k] + c * 32);
        }
    };
    auto stage_write = [&](int nbuf, short8* v) {
#pragma unroll
        for (int k = 0; k < 3; ++k)
            if (t_dst[k] >= 0)
                *(short8*)&lds[nbuf][t_dst[k]] = v[k];
    };

    auto compute = [&](int cb, int c) {
        const ushort* lbase = lds[cb];
#pragma unroll
        for (int t = 0; t < 9; ++t) {
            int ky = t / 3, kx = t % 3;
            short8 a[4], bv[4];
#pragma unroll
            for (int mi = 0; mi < 4; ++mi)
                a[mi] = *(const short8*)(wpk +
                        ((size_t)((t * 8 + c) * 128 + wM * 64 + mi * 16 + l15)) * 32
                        + l4 * 8);
#pragma unroll
            for (int ni = 0; ni < 4; ++ni) {
                int oy = wN * 4 + ni;
                int ipx = (oy + ky) * 18 + l15 + kx;
                bv[ni] = *(const short8*)&lbase[ipx * 32
                        + ((l4 ^ ((ipx >> 1) & 3)) * 8)];
            }
#pragma unroll
            for (int mi = 0; mi < 4; ++mi)
#pragma unroll
                for (int ni = 0; ni < 4; ++ni)
                    acc[mi][ni] = __builtin_amdgcn_mfma_f32_16x16x32_bf16(
                        a[mi], bv[ni], acc[mi][ni], 0, 0, 0);
        }
    };

    {
        short8 sv[3];
        stage_load(0, sv);
        stage_write(0, sv);
    }
    __syncthreads();
    for (int c = 0; c < 8; ++c) {
        short8 nv[3];
        if (c < 7) stage_load(c + 1, nv);
        compute(c & 1, c);
        if (c < 7) stage_write((c + 1) & 1, nv);
        __syncthreads();
    }

    size_t ob = (size_t)b * OUTC * HW + (size_t)281 * HW;
#pragma unroll
    for (int mi = 0; mi < 4; ++mi)
#pragma unroll
        for (int ni = 0; ni < 4; ++ni) {
            int gy = y0 + wN * 4 + ni, gx = x0 + l15;
#pragma unroll
            for (int r = 0; r < 4; ++r) {
                int oc = wM * 64 + mi * 16 + l4 * 4 + r;
                float v = acc[mi][ni][r] + b1[oc];
                outp[ob + (size_t)oc * HW + (size_t)gy * Ww + gx] = fmaxf(v, 0.f);
            }
        }
}

extern "C" void kernel_launch(void* const* d_in, const int* in_sizes, int n_in,
                              void* d_out, int out_size, void* d_ws, size_t ws_size,
                              hipStream_t stream) {
    const float* feat = (const float*)d_in[0];
    const float* w0   = (const float*)d_in[1];
    const float* b0   = (const float*)d_in[2];
    const float* w1   = (const float*)d_in[3];
    const float* b1   = (const float*)d_in[4];
    float* out = (float*)d_out;

    // ws: wpk0 (147456) | wpk1 (589824) | sspk (37748736) | fnorm (75497472)
    ushort* wpk0  = (ushort*)d_ws;
    ushort* wpk1  = (ushort*)((char*)d_ws + 147456);
    ushort* sspk  = (ushort*)((char*)d_ws + 147456 + 589824);
    ushort* fnorm = (ushort*)((char*)d_ws + 147456 + 589824 + 37748736);

    hipLaunchKernelGGL(kwpack0, dim3(288),  dim3(256), 0, stream, w0, wpk0);
    hipLaunchKernelGGL(kwpack1, dim3(1152), dim3(256), 0, stream, w1, wpk1);
    hipLaunchKernelGGL(kpack,   dim3(HW / PKPX, NB), dim3(256), 0, stream, feat, fnorm);
    hipLaunchKernelGGL(kss4,    dim3(12, 12, NB), dim3(256), 0, stream, fnorm, out);
    hipLaunchKernelGGL(kconv1m, dim3(12, 12, NB), dim3(256), 0, stream, out, wpk0, b0, out, sspk);
    hipLaunchKernelGGL(kconv2n, dim3(6, 12, NB), dim3(256), 0, stream, sspk, wpk1, b1, out);
}

// Round 2
// 265.639 us; speedup vs baseline: 1.3321x; 1.2256x over previous
//
#include <hip/hip_runtime.h>

#define FEAT_C 512
#define Hh 96
#define Ww 96
#define HW (Hh*Ww)
#define NB 8
#define OUTC 409

typedef __attribute__((ext_vector_type(8))) short short8;
typedef __attribute__((ext_vector_type(4))) short short4v;
typedef __attribute__((ext_vector_type(4))) float f32x4;
typedef __fp16 h2 __attribute__((ext_vector_type(2)));
typedef __fp16 h8 __attribute__((ext_vector_type(8)));

typedef __attribute__((address_space(1))) const unsigned int gu32;
typedef __attribute__((address_space(3))) unsigned int lu32;

__device__ inline ushort f2bf(float x) {
    unsigned u = __float_as_uint(x);
    u += 0x7fffu + ((u >> 16) & 1u);
    return (ushort)(u >> 16);
}

#if __has_builtin(__builtin_amdgcn_fdot2)
__device__ inline float FDOT2(h2 a, h2 b, float c) {
    return __builtin_amdgcn_fdot2(a, b, c, false);
}
#else
__device__ inline float FDOT2(h2 a, h2 b, float c) {
    return c + (float)a[0] * (float)b[0] + (float)a[1] * (float)b[1];
}
#endif

__device__ inline h2 pair(h8 v, int i) {
    switch (i) {
        case 0: return __builtin_shufflevector(v, v, 0, 1);
        case 1: return __builtin_shufflevector(v, v, 2, 3);
        case 2: return __builtin_shufflevector(v, v, 4, 5);
        default: return __builtin_shufflevector(v, v, 6, 7);
    }
}

// ============ kpack: normalize + transpose feature ========================
#define PKPX 32
__global__ __launch_bounds__(256) void kpack(const float* __restrict__ f,
                                             ushort* __restrict__ fnorm) {
    __shared__ ushort tr[PKPX * 512];      // 32 KB
    __shared__ float ssqp[8][PKPX];
    __shared__ float sinvs[PKPX];
    int tid = threadIdx.x;
    int g = tid >> 5, pl = tid & 31;
    int b = blockIdx.y;
    int p0 = blockIdx.x * PKPX;
    const float* fb = f + (size_t)b * FEAT_C * HW + p0 + pl;

    float ssq = 0.f;
#pragma unroll
    for (int q = 0; q < 8; ++q) {
        int u = g * 8 + q;
        float v[8];
#pragma unroll
        for (int j = 0; j < 8; ++j)
            v[j] = fb[(size_t)(u * 8 + j) * HW];
        h2 a0 = __builtin_amdgcn_cvt_pkrtz(v[0], v[1]);
        h2 a1 = __builtin_amdgcn_cvt_pkrtz(v[2], v[3]);
        h2 a2 = __builtin_amdgcn_cvt_pkrtz(v[4], v[5]);
        h2 a3 = __builtin_amdgcn_cvt_pkrtz(v[6], v[7]);
        ssq = FDOT2(a0, a0, ssq); ssq = FDOT2(a1, a1, ssq);
        ssq = FDOT2(a2, a2, ssq); ssq = FDOT2(a3, a3, ssq);
        h8 hv;
        hv[0] = a0[0]; hv[1] = a0[1]; hv[2] = a1[0]; hv[3] = a1[1];
        hv[4] = a2[0]; hv[5] = a2[1]; hv[6] = a3[0]; hv[7] = a3[1];
        int up = u ^ (pl & 7);
        *(h8*)&tr[pl * 512 + up * 8] = hv;
    }
    ssqp[g][pl] = ssq;
    __syncthreads();
    if (tid < PKPX) {
        float s = 0.f;
#pragma unroll
        for (int gg = 0; gg < 8; ++gg) s += ssqp[gg][tid];
        sinvs[tid] = 1.0f / fmaxf(sqrtf(s), 1e-12f);
    }
    __syncthreads();

    size_t ob = ((size_t)b * HW + p0) * 512;
#pragma unroll
    for (int i = 0; i < 8; ++i) {
        int t = tid + i * 256;
        int r = t >> 6, k = t & 63;
        h8 hv = *(const h8*)&tr[r * 512 + ((k ^ (r & 7)) * 8)];
        float s = sinvs[r];
        h2 o0 = __builtin_amdgcn_cvt_pkrtz((float)hv[0] * s, (float)hv[1] * s);
        h2 o1 = __builtin_amdgcn_cvt_pkrtz((float)hv[2] * s, (float)hv[3] * s);
        h2 o2 = __builtin_amdgcn_cvt_pkrtz((float)hv[4] * s, (float)hv[5] * s);
        h2 o3 = __builtin_amdgcn_cvt_pkrtz((float)hv[6] * s, (float)hv[7] * s);
        h8 ov;
        ov[0] = o0[0]; ov[1] = o0[1]; ov[2] = o1[0]; ov[3] = o1[1];
        ov[4] = o2[0]; ov[5] = o2[1]; ov[6] = o3[0]; ov[7] = o3[1];
        *(h8*)&fnorm[ob + (size_t)r * 512 + k * 8] = ov;
    }
}

// ============ kss4: self-similarity from packed normalized f16 ============
#define SS_NT4 576

__global__ __launch_bounds__(256) void kss4(const ushort* __restrict__ fnorm,
                                            float* __restrict__ out) {
    __shared__ ushort tile[2][144 * 32];
    int tid = threadIdx.x;
    int w = tid >> 6, lane = tid & 63;
    int slab = (lane >> 4) & 3, p16 = lane & 15;
    int ox = p16 & 7, oy = 2 * w + (p16 >> 3);
    int x0 = blockIdx.x * 8, y0 = blockIdx.y * 8, b = blockIdx.z;

    const ushort* t_src[3];
    int t_dst[3];
    bool t_ok[3];
#pragma unroll
    for (int k = 0; k < 3; ++k) {
        int task = tid + k * 256;
        t_ok[k] = false; t_src[k] = fnorm; t_dst[k] = 0;
        if (task < SS_NT4) {
            int icg = task & 3, pix = task >> 2;
            int hrow = pix / 12, hcol = pix % 12;
            int gy = y0 + hrow - 2, gx = x0 + hcol - 2;
            t_dst[k] = task * 8;
            if (gy >= 0 && gy < Hh && gx >= 0 && gx < Ww) {
                t_ok[k] = true;
                t_src[k] = fnorm + ((size_t)b * HW + (size_t)gy * Ww + gx) * 512
                         + icg * 8;
            }
        } else {
            t_dst[k] = -1;
        }
    }

    float acc[25];
#pragma unroll
    for (int o = 0; o < 25; ++o) acc[o] = 0.f;

    auto stage = [&](int chunk, int nbuf) {
        short8 v[3];
#pragma unroll
        for (int k = 0; k < 3; ++k) {
            v[k] = (short8)0;
            if (t_ok[k]) v[k] = *(const short8*)(t_src[k] + chunk * 32);
        }
#pragma unroll
        for (int k = 0; k < 3; ++k)
            if (t_dst[k] >= 0)
                *(short8*)&tile[nbuf][t_dst[k]] = v[k];
    };

    int pc = (oy + 2) * 12 + (ox + 2);
    auto compute = [&](int kb) {
        const ushort* tb = &tile[kb][slab * 8];
        h8 ctr = *(const h8*)(tb + pc * 32);
#pragma unroll
        for (int dx = 0; dx < 5; ++dx)
#pragma unroll
            for (int dy = 0; dy < 5; ++dy) {
                int pn = (oy + dy) * 12 + (ox + dx);
                h8 nbv = *(const h8*)(tb + pn * 32);
                float a = acc[dx * 5 + dy];
                a = FDOT2(pair(nbv, 0), pair(ctr, 0), a);
                a = FDOT2(pair(nbv, 1), pair(ctr, 1), a);
                a = FDOT2(pair(nbv, 2), pair(ctr, 2), a);
                a = FDOT2(pair(nbv, 3), pair(ctr, 3), a);
                acc[dx * 5 + dy] = a;
            }
    };

    stage(0, 0);
    __syncthreads();
    for (int c = 0; c < 16; ++c) {
        if (c < 15) stage(c + 1, (c + 1) & 1);
        compute(c & 1);
        __syncthreads();
    }

    size_t ob = (size_t)b * OUTC * HW + (size_t)(y0 + oy) * Ww + (x0 + ox);
#pragma unroll
    for (int dx = 0; dx < 5; ++dx)
#pragma unroll
        for (int dy = 0; dy < 5; ++dy) {
            int o = dx * 5 + dy;
            float v = acc[o];
            v += __shfl_xor(v, 16);
            v += __shfl_xor(v, 32);
            if (slab == 0)
                out[ob + (size_t)o * HW] = v;
        }
}

// ============ weight repacks ==============================================
__global__ __launch_bounds__(256) void kwpack0(const float* __restrict__ w0,
                                               ushort* __restrict__ wpk0) {
    int i = blockIdx.x * 256 + threadIdx.x;
    if (i >= 9 * 256 * 32) return;
    int ic = i & 31, oc = (i >> 5) & 255, t = i >> 13;
    wpk0[i] = (ic < 25) ? f2bf(w0[(size_t)oc * 225 + ic * 9 + t]) : (ushort)0;
}

// w1 [128][256][3][3] f32 -> wpk1 [8 chunk][3 ky][3 kx][128 oc][4 slot][8]
// bf16, with the ds_read-side bank swizzle BAKED IN: slot s holds source
// ic-unit u = s ^ ((oc>>1)&3)  (global_load_lds writes LDS linearly, so the
// swizzle must live in the global layout — both-sides-or-neither).
__global__ __launch_bounds__(256) void kwpack1(const float* __restrict__ w1,
                                               ushort* __restrict__ wpk1) {
    int i = blockIdx.x * 256 + threadIdx.x;
    if (i >= 8 * 9 * 128 * 32) return;
    int ct = i >> 12;                 // (c*9 + t), 128*32 = 4096
    int c = ct / 9, t = ct % 9;
    int oc = (i >> 5) & 127;
    int s = (i >> 3) & 3, ii = i & 7;
    int u = s ^ ((oc >> 1) & 3);
    int ic = c * 32 + u * 8 + ii;
    wpk1[i] = f2bf(w1[((size_t)oc * 256 + ic) * 9 + t]);
}

// ============ kconv1m: 25->256 conv via MFMA ==============================
#define C1PAD 40
__global__ __launch_bounds__(256) void kconv1m(const float* __restrict__ ssin,
                                               const ushort* __restrict__ wpk0,
                                               const float* __restrict__ b0,
                                               float* __restrict__ outp,
                                               ushort* __restrict__ sspk) {
    __shared__ ushort wtile[100][C1PAD];
    int tid = threadIdx.x;
    int lane = tid & 63, wM = tid >> 6;
    int l15 = lane & 15, l4 = lane >> 4;
    int x0 = blockIdx.x * 8, y0 = blockIdx.y * 8, b = blockIdx.z;

    const float* sb = ssin + (size_t)b * OUTC * HW;
    if (tid < 100) {
        int py = tid / 10, px = tid % 10;
        int gy = y0 + py - 1, gx = x0 + px - 1;
        ushort row[32];
        bool ok = (gy >= 0 && gy < Hh && gx >= 0 && gx < Ww);
        int gyx = ok ? gy * Ww + gx : 0;
#pragma unroll
        for (int o = 0; o < 25; ++o)
            row[o] = ok ? f2bf(sb[(size_t)o * HW + gyx]) : (ushort)0;
#pragma unroll
        for (int o = 25; o < 32; ++o) row[o] = 0;
#pragma unroll
        for (int q = 0; q < 4; ++q)
            *(short8*)&wtile[tid][q * 8] = *(short8*)&row[q * 8];
    }
    __syncthreads();

    f32x4 acc[4][4];
#pragma unroll
    for (int mi = 0; mi < 4; ++mi)
#pragma unroll
        for (int ni = 0; ni < 4; ++ni)
            acc[mi][ni] = (f32x4)0.f;

#pragma unroll
    for (int t = 0; t < 9; ++t) {
        int ky = t / 3, kx = t % 3;
        short8 a[4], bv[4];
#pragma unroll
        for (int mi = 0; mi < 4; ++mi)
            a[mi] = *(const short8*)(wpk0 +
                    ((size_t)(t * 256 + wM * 64 + mi * 16 + l15)) * 32 + l4 * 8);
#pragma unroll
        for (int ni = 0; ni < 4; ++ni) {
            int px_id = ni * 16 + l15;
            int pn = (px_id / 8 + ky) * 10 + (px_id & 7) + kx;
            bv[ni] = *(const short8*)&wtile[pn][l4 * 8];
        }
#pragma unroll
        for (int mi = 0; mi < 4; ++mi)
#pragma unroll
            for (int ni = 0; ni < 4; ++ni)
                acc[mi][ni] = __builtin_amdgcn_mfma_f32_16x16x32_bf16(
                    a[mi], bv[ni], acc[mi][ni], 0, 0, 0);
    }

    size_t ob = (size_t)b * OUTC * HW + (size_t)25 * HW;
    size_t pb = (size_t)b * HW;
#pragma unroll
    for (int mi = 0; mi < 4; ++mi)
#pragma unroll
        for (int ni = 0; ni < 4; ++ni) {
            int px_id = ni * 16 + l15;
            int gy = y0 + (px_id >> 3), gx = x0 + (px_id & 7);
            int oc_b = wM * 64 + mi * 16 + l4 * 4;
            short4v hv;
#pragma unroll
            for (int r = 0; r < 4; ++r) {
                float v = fmaxf(acc[mi][ni][r] + b0[oc_b + r], 0.f);
                outp[ob + (size_t)(oc_b + r) * HW + (size_t)gy * Ww + gx] = v;
                hv[r] = (short)f2bf(v);
            }
            *(short4v*)&sspk[(pb + (size_t)gy * Ww + gx) * 256 + oc_b] = hv;
        }
}

// ============ kconv2n: 256->128 conv via MFMA, 16x8 tile ==================
// grid (6,12,NB); 4 waves: wM = oc-half (64 oc), wN = row-half (64 px).
// Weights no longer dependent-use global loads: cooperatively DMA'd into
// LDS via global_load_lds (16B), double-buffered per tap-GROUP (one ky row
// = 3 taps = 24 KB), prefetched one group ahead so the 48-MFMA compute
// phase hides L2 latency. A-frag ds_read uses slot = l4 ^ ((oc>>1)&3)
// (baked into wpk1): every consecutive 8-lane group covers all 8 bank
// granules -> conflict-free. LDS = 2x24K weights + 2x11.5K pixels = 71 KB
// -> 2 blocks/CU (unchanged occupancy).
#define NPX2 180
#define WGRP 12288   // ushorts per 24 KB weight group (3 taps x 128 x 32)
__global__ __launch_bounds__(256, 2) void kconv2n(const ushort* __restrict__ sspk,
                                                  const ushort* __restrict__ wpk,
                                                  const float* __restrict__ b1,
                                                  float* __restrict__ outp) {
    __shared__ ushort wlds[2][WGRP];       // 2 x 24 KB
    __shared__ ushort plds[2][NPX2 * 32];  // 2 x 11.52 KB
    int tid = threadIdx.x;
    int lane = tid & 63, wid = tid >> 6;
    int wM = wid >> 1, wN = wid & 1;
    int l15 = lane & 15, l4 = lane >> 4;
    int x0 = blockIdx.x * 16, y0 = blockIdx.y * 8, b = blockIdx.z;

    f32x4 acc[4][4];
#pragma unroll
    for (int mi = 0; mi < 4; ++mi)
#pragma unroll
        for (int ni = 0; ni < 4; ++ni)
            acc[mi][ni] = (f32x4)0.f;

    // pixel staging: 720 16B-units per chunk (180 px x 4 units), 3 tasks/thr
    size_t t_src[3];
    int t_dst[3];
    bool t_ok[3];
#pragma unroll
    for (int k = 0; k < 3; ++k) {
        int task = tid + k * 256;
        t_ok[k] = false; t_src[k] = 0; t_dst[k] = -1;
        if (task < 720) {
            int px = task >> 2, u = task & 3;
            int iy = px / 18, ix = px % 18;
            int gy = y0 + iy - 1, gx = x0 + ix - 1;
            t_dst[k] = px * 32 + (u ^ ((px >> 1) & 3)) * 8;
            if (gy >= 0 && gy < Hh && gx >= 0 && gx < Ww) {
                t_ok[k] = true;
                t_src[k] = ((size_t)b * HW + (size_t)gy * Ww + gx) * 256 + u * 8;
            }
        }
    }

    auto stage_load = [&](int c, short8* v) {
#pragma unroll
        for (int k = 0; k < 3; ++k) {
            v[k] = (short8)0;
            if (t_ok[k])
                v[k] = *(const short8*)(sspk + t_src[k] + c * 32);
        }
    };
    auto stage_write = [&](int nbuf, short8* v) {
#pragma unroll
        for (int k = 0; k < 3; ++k)
            if (t_dst[k] >= 0)
                *(short8*)&plds[nbuf][t_dst[k]] = v[k];
    };

    // cooperative weight DMA: group gi (24 KB) -> wlds[buf]; 6 x 1KB per wave
    auto wstage = [&](int gi, int buf) {
        const ushort* src = wpk + (size_t)gi * WGRP + wid * 3072 + lane * 8;
        ushort* dst = &wlds[buf][wid * 3072];
#pragma unroll
        for (int i = 0; i < 6; ++i)
            __builtin_amdgcn_global_load_lds((gu32*)(src + i * 512),
                                             (lu32*)(dst + i * 512), 16, 0, 0);
    };

    int wslot = l4 ^ ((l15 >> 1) & 3);
    auto compute = [&](int wb, int pb_, int ky) {
        const ushort* wbase = wlds[wb];
        const ushort* lbase = plds[pb_];
#pragma unroll
        for (int kx = 0; kx < 3; ++kx) {
            short8 a[4], bv[4];
#pragma unroll
            for (int mi = 0; mi < 4; ++mi) {
                int row = wM * 64 + mi * 16 + l15;
                a[mi] = *(const short8*)&wbase[(kx * 128 + row) * 32 + wslot * 8];
            }
#pragma unroll
            for (int ni = 0; ni < 4; ++ni) {
                int oy = wN * 4 + ni;
                int ipx = (oy + ky) * 18 + l15 + kx;
                bv[ni] = *(const short8*)&lbase[ipx * 32
                        + ((l4 ^ ((ipx >> 1) & 3)) * 8)];
            }
#pragma unroll
            for (int mi = 0; mi < 4; ++mi)
#pragma unroll
                for (int ni = 0; ni < 4; ++ni)
                    acc[mi][ni] = __builtin_amdgcn_mfma_f32_16x16x32_bf16(
                        a[mi], bv[ni], acc[mi][ni], 0, 0, 0);
        }
    };

    // prologue: weights group 0 + pixel chunk 0
    wstage(0, 0);
    {
        short8 sv[3];
        stage_load(0, sv);
        stage_write(0, sv);
    }
    __syncthreads();

    for (int c = 0; c < 8; ++c) {
        int gi = c * 3;
        short8 nv[3];
        // g = 0
        wstage(gi + 1, (gi + 1) & 1);
        if (c < 7) stage_load(c + 1, nv);
        compute(gi & 1, c & 1, 0);
        __syncthreads();
        // g = 1
        wstage(gi + 2, (gi + 2) & 1);
        compute((gi + 1) & 1, c & 1, 1);
        __syncthreads();
        // g = 2
        if (gi + 3 < 24) wstage(gi + 3, (gi + 3) & 1);
        if (c < 7) stage_write((c + 1) & 1, nv);
        compute((gi + 2) & 1, c & 1, 2);
        __syncthreads();
    }

    size_t ob = (size_t)b * OUTC * HW + (size_t)281 * HW;
#pragma unroll
    for (int mi = 0; mi < 4; ++mi)
#pragma unroll
        for (int ni = 0; ni < 4; ++ni) {
            int gy = y0 + wN * 4 + ni, gx = x0 + l15;
#pragma unroll
            for (int r = 0; r < 4; ++r) {
                int oc = wM * 64 + mi * 16 + l4 * 4 + r;
                float v = acc[mi][ni][r] + b1[oc];
                outp[ob + (size_t)oc * HW + (size_t)gy * Ww + gx] = fmaxf(v, 0.f);
            }
        }
}

extern "C" void kernel_launch(void* const* d_in, const int* in_sizes, int n_in,
                              void* d_out, int out_size, void* d_ws, size_t ws_size,
                              hipStream_t stream) {
    const float* feat = (const float*)d_in[0];
    const float* w0   = (const float*)d_in[1];
    const float* b0   = (const float*)d_in[2];
    const float* w1   = (const float*)d_in[3];
    const float* b1   = (const float*)d_in[4];
    float* out = (float*)d_out;

    // ws: wpk0 (147456) | wpk1 (589824) | sspk (37748736) | fnorm (75497472)
    ushort* wpk0  = (ushort*)d_ws;
    ushort* wpk1  = (ushort*)((char*)d_ws + 147456);
    ushort* sspk  = (ushort*)((char*)d_ws + 147456 + 589824);
    ushort* fnorm = (ushort*)((char*)d_ws + 147456 + 589824 + 37748736);

    hipLaunchKernelGGL(kwpack0, dim3(288),  dim3(256), 0, stream, w0, wpk0);
    hipLaunchKernelGGL(kwpack1, dim3(1152), dim3(256), 0, stream, w1, wpk1);
    hipLaunchKernelGGL(kpack,   dim3(HW / PKPX, NB), dim3(256), 0, stream, feat, fnorm);
    hipLaunchKernelGGL(kss4,    dim3(12, 12, NB), dim3(256), 0, stream, fnorm, out);
    hipLaunchKernelGGL(kconv1m, dim3(12, 12, NB), dim3(256), 0, stream, out, wpk0, b0, out, sspk);
    hipLaunchKernelGGL(kconv2n, dim3(6, 12, NB), dim3(256), 0, stream, sspk, wpk1, b1, out);
}

// Round 3
// 209.732 us; speedup vs baseline: 1.6872x; 1.2666x over previous
//
#include <hip/hip_runtime.h>

#define FEAT_C 512
#define Hh 96
#define Ww 96
#define HW (Hh*Ww)
#define NB 8
#define OUTC 409

typedef __attribute__((ext_vector_type(8))) short short8;
typedef __attribute__((ext_vector_type(4))) short short4v;
typedef __attribute__((ext_vector_type(4))) float f32x4;
typedef __fp16 h2 __attribute__((ext_vector_type(2)));
typedef __fp16 h8 __attribute__((ext_vector_type(8)));

typedef __attribute__((address_space(1))) const unsigned int gu32;
typedef __attribute__((address_space(3))) unsigned int lu32;

__device__ inline ushort f2bf(float x) {
    unsigned u = __float_as_uint(x);
    u += 0x7fffu + ((u >> 16) & 1u);
    return (ushort)(u >> 16);
}

#if __has_builtin(__builtin_amdgcn_fdot2)
__device__ inline float FDOT2(h2 a, h2 b, float c) {
    return __builtin_amdgcn_fdot2(a, b, c, false);
}
#else
__device__ inline float FDOT2(h2 a, h2 b, float c) {
    return c + (float)a[0] * (float)b[0] + (float)a[1] * (float)b[1];
}
#endif

__device__ inline h2 pair(h8 v, int i) {
    switch (i) {
        case 0: return __builtin_shufflevector(v, v, 0, 1);
        case 1: return __builtin_shufflevector(v, v, 2, 3);
        case 2: return __builtin_shufflevector(v, v, 4, 5);
        default: return __builtin_shufflevector(v, v, 6, 7);
    }
}

// ============ kpack: normalize + transpose feature ========================
#define PKPX 32
__global__ __launch_bounds__(256) void kpack(const float* __restrict__ f,
                                             ushort* __restrict__ fnorm) {
    __shared__ ushort tr[PKPX * 512];      // 32 KB
    __shared__ float ssqp[8][PKPX];
    __shared__ float sinvs[PKPX];
    int tid = threadIdx.x;
    int g = tid >> 5, pl = tid & 31;
    int b = blockIdx.y;
    int p0 = blockIdx.x * PKPX;
    const float* fb = f + (size_t)b * FEAT_C * HW + p0 + pl;

    float ssq = 0.f;
#pragma unroll
    for (int q = 0; q < 8; ++q) {
        int u = g * 8 + q;
        float v[8];
#pragma unroll
        for (int j = 0; j < 8; ++j)
            v[j] = fb[(size_t)(u * 8 + j) * HW];
        h2 a0 = __builtin_amdgcn_cvt_pkrtz(v[0], v[1]);
        h2 a1 = __builtin_amdgcn_cvt_pkrtz(v[2], v[3]);
        h2 a2 = __builtin_amdgcn_cvt_pkrtz(v[4], v[5]);
        h2 a3 = __builtin_amdgcn_cvt_pkrtz(v[6], v[7]);
        ssq = FDOT2(a0, a0, ssq); ssq = FDOT2(a1, a1, ssq);
        ssq = FDOT2(a2, a2, ssq); ssq = FDOT2(a3, a3, ssq);
        h8 hv;
        hv[0] = a0[0]; hv[1] = a0[1]; hv[2] = a1[0]; hv[3] = a1[1];
        hv[4] = a2[0]; hv[5] = a2[1]; hv[6] = a3[0]; hv[7] = a3[1];
        int up = u ^ (pl & 7);
        *(h8*)&tr[pl * 512 + up * 8] = hv;
    }
    ssqp[g][pl] = ssq;
    __syncthreads();
    if (tid < PKPX) {
        float s = 0.f;
#pragma unroll
        for (int gg = 0; gg < 8; ++gg) s += ssqp[gg][tid];
        sinvs[tid] = 1.0f / fmaxf(sqrtf(s), 1e-12f);
    }
    __syncthreads();

    size_t ob = ((size_t)b * HW + p0) * 512;
#pragma unroll
    for (int i = 0; i < 8; ++i) {
        int t = tid + i * 256;
        int r = t >> 6, k = t & 63;
        h8 hv = *(const h8*)&tr[r * 512 + ((k ^ (r & 7)) * 8)];
        float s = sinvs[r];
        h2 o0 = __builtin_amdgcn_cvt_pkrtz((float)hv[0] * s, (float)hv[1] * s);
        h2 o1 = __builtin_amdgcn_cvt_pkrtz((float)hv[2] * s, (float)hv[3] * s);
        h2 o2 = __builtin_amdgcn_cvt_pkrtz((float)hv[4] * s, (float)hv[5] * s);
        h2 o3 = __builtin_amdgcn_cvt_pkrtz((float)hv[6] * s, (float)hv[7] * s);
        h8 ov;
        ov[0] = o0[0]; ov[1] = o0[1]; ov[2] = o1[0]; ov[3] = o1[1];
        ov[4] = o2[0]; ov[5] = o2[1]; ov[6] = o3[0]; ov[7] = o3[1];
        *(h8*)&fnorm[ob + (size_t)r * 512 + k * 8] = ov;
    }
}

// ============ kss4: self-similarity; writes f32 planes + bf16 packed ======
#define SS_NT4 576

__global__ __launch_bounds__(256) void kss4(const ushort* __restrict__ fnorm,
                                            float* __restrict__ out,
                                            ushort* __restrict__ sspk0) {
    __shared__ ushort tile[2][144 * 32];
    int tid = threadIdx.x;
    int w = tid >> 6, lane = tid & 63;
    int slab = (lane >> 4) & 3, p16 = lane & 15;
    int ox = p16 & 7, oy = 2 * w + (p16 >> 3);
    int x0 = blockIdx.x * 8, y0 = blockIdx.y * 8, b = blockIdx.z;

    const ushort* t_src[3];
    int t_dst[3];
    bool t_ok[3];
#pragma unroll
    for (int k = 0; k < 3; ++k) {
        int task = tid + k * 256;
        t_ok[k] = false; t_src[k] = fnorm; t_dst[k] = 0;
        if (task < SS_NT4) {
            int icg = task & 3, pix = task >> 2;
            int hrow = pix / 12, hcol = pix % 12;
            int gy = y0 + hrow - 2, gx = x0 + hcol - 2;
            t_dst[k] = task * 8;
            if (gy >= 0 && gy < Hh && gx >= 0 && gx < Ww) {
                t_ok[k] = true;
                t_src[k] = fnorm + ((size_t)b * HW + (size_t)gy * Ww + gx) * 512
                         + icg * 8;
            }
        } else {
            t_dst[k] = -1;
        }
    }

    float acc[25];
#pragma unroll
    for (int o = 0; o < 25; ++o) acc[o] = 0.f;

    auto stage = [&](int chunk, int nbuf) {
        short8 v[3];
#pragma unroll
        for (int k = 0; k < 3; ++k) {
            v[k] = (short8)0;
            if (t_ok[k]) v[k] = *(const short8*)(t_src[k] + chunk * 32);
        }
#pragma unroll
        for (int k = 0; k < 3; ++k)
            if (t_dst[k] >= 0)
                *(short8*)&tile[nbuf][t_dst[k]] = v[k];
    };

    int pc = (oy + 2) * 12 + (ox + 2);
    auto compute = [&](int kb) {
        const ushort* tb = &tile[kb][slab * 8];
        h8 ctr = *(const h8*)(tb + pc * 32);
#pragma unroll
        for (int dx = 0; dx < 5; ++dx)
#pragma unroll
            for (int dy = 0; dy < 5; ++dy) {
                int pn = (oy + dy) * 12 + (ox + dx);
                h8 nbv = *(const h8*)(tb + pn * 32);
                float a = acc[dx * 5 + dy];
                a = FDOT2(pair(nbv, 0), pair(ctr, 0), a);
                a = FDOT2(pair(nbv, 1), pair(ctr, 1), a);
                a = FDOT2(pair(nbv, 2), pair(ctr, 2), a);
                a = FDOT2(pair(nbv, 3), pair(ctr, 3), a);
                acc[dx * 5 + dy] = a;
            }
    };

    stage(0, 0);
    __syncthreads();
    for (int c = 0; c < 16; ++c) {
        if (c < 15) stage(c + 1, (c + 1) & 1);
        compute(c & 1);
        __syncthreads();
    }

    // reduce across slabs; slab0 lanes hold final 25 values for their pixel
#pragma unroll
    for (int o = 0; o < 25; ++o) {
        float v = acc[o];
        v += __shfl_xor(v, 16);
        v += __shfl_xor(v, 32);
        acc[o] = v;
    }
    if (slab == 0) {
        size_t pxid = (size_t)b * HW + (size_t)(y0 + oy) * Ww + (x0 + ox);
        size_t ob = (size_t)b * OUTC * HW + (size_t)(y0 + oy) * Ww + (x0 + ox);
#pragma unroll
        for (int o = 0; o < 25; ++o)
            out[ob + (size_t)o * HW] = acc[o];
        ushort pk[32];
#pragma unroll
        for (int o = 0; o < 25; ++o) pk[o] = f2bf(acc[o]);
#pragma unroll
        for (int o = 25; o < 32; ++o) pk[o] = 0;
#pragma unroll
        for (int u = 0; u < 4; ++u)
            *(short8*)&sspk0[pxid * 32 + u * 8] = *(short8*)&pk[u * 8];
    }
}

// ============ weight repacks ==============================================
// w0 [256][25][3][3] f32 -> wpk0 [9 t][256 oc][4 slot][8] bf16 with the
// ds_read bank swizzle BAKED IN: slot s holds ic-unit u = s ^ ((oc>>1)&3)
// (global_load_lds writes LDS linearly -> swizzle lives in global layout).
__global__ __launch_bounds__(256) void kwpack0(const float* __restrict__ w0,
                                               ushort* __restrict__ wpk0) {
    int i = blockIdx.x * 256 + threadIdx.x;
    if (i >= 9 * 256 * 32) return;
    int t = i >> 13, oc = (i >> 5) & 255;
    int s = (i >> 3) & 3, ii = i & 7;
    int u = s ^ ((oc >> 1) & 3);
    int ic = u * 8 + ii;
    wpk0[i] = (ic < 25) ? f2bf(w0[(size_t)oc * 225 + ic * 9 + t]) : (ushort)0;
}

// w1 [128][256][3][3] f32 -> wpk1 [8 chunk][3 ky][3 kx][128 oc][4 slot][8]
// bf16, same baked swizzle u = s ^ ((oc>>1)&3).
__global__ __launch_bounds__(256) void kwpack1(const float* __restrict__ w1,
                                               ushort* __restrict__ wpk1) {
    int i = blockIdx.x * 256 + threadIdx.x;
    if (i >= 8 * 9 * 128 * 32) return;
    int ct = i >> 12;                 // (c*9 + t), 128*32 = 4096
    int c = ct / 9, t = ct % 9;
    int oc = (i >> 5) & 127;
    int s = (i >> 3) & 3, ii = i & 7;
    int u = s ^ ((oc >> 1) & 3);
    int ic = c * 32 + u * 8 + ii;
    wpk1[i] = f2bf(w1[((size_t)oc * 256 + ic) * 9 + t]);
}

// ============ kconv1m: 25->256 conv via MFMA, 16x8 tile, 512 thr ==========
// grid (6,12,NB); 8 waves: wM=wid>>1 (64 oc), wN=wid&1 (4 rows x 16 px).
// Pixels: vectorized 16B loads from bf16-packed sspk0 (written by kss4),
// reg-staged with write-side XOR swizzle -> conflict-free ds_read_b128.
// Weights: global_load_lds DMA, double-buffered per 3x3-tap (16 KB),
// prefetched one tap ahead; read-slot swizzle baked into wpk0 layout.
#define C1NPX 180
__global__ __launch_bounds__(512, 2) void kconv1m(const ushort* __restrict__ sspk0,
                                                  const ushort* __restrict__ wpk0,
                                                  const float* __restrict__ b0,
                                                  float* __restrict__ outp,
                                                  ushort* __restrict__ sspk) {
    __shared__ ushort wlds[2][8192];      // 2 x 16 KB (one tap: 256 oc x 32)
    __shared__ ushort plds[C1NPX * 32];   // 11.52 KB
    int tid = threadIdx.x;
    int lane = tid & 63, wid = tid >> 6;
    int wM = wid >> 1, wN = wid & 1;
    int l15 = lane & 15, l4 = lane >> 4;
    int x0 = blockIdx.x * 16, y0 = blockIdx.y * 8, b = blockIdx.z;

    // weight DMA: tap t (16 KB = 1024 16B-units) -> wlds[buf]; 2 units/thread
    auto wstage = [&](int t, int buf) {
        const ushort* src = wpk0 + (size_t)t * 8192 + wid * 1024 + lane * 8;
        ushort* dst = &wlds[buf][wid * 1024];
#pragma unroll
        for (int i = 0; i < 2; ++i)
            __builtin_amdgcn_global_load_lds((gu32*)(src + i * 512),
                                             (lu32*)(dst + i * 512), 16, 0, 0);
    };

    wstage(0, 0);

    // pixel staging: 720 16B-units (180 px x 4), swizzled LDS dst
    {
        short8 v[2]; int dst[2];
#pragma unroll
        for (int k = 0; k < 2; ++k) {
            int task = tid + k * 512;
            v[k] = (short8)0; dst[k] = -1;
            if (task < 720) {
                int px = task >> 2, u = task & 3;
                int iy = px / 18, ix = px % 18;
                int gy = y0 + iy - 1, gx = x0 + ix - 1;
                dst[k] = px * 32 + (u ^ ((px >> 1) & 3)) * 8;
                if (gy >= 0 && gy < Hh && gx >= 0 && gx < Ww)
                    v[k] = *(const short8*)(sspk0 +
                            ((size_t)b * HW + (size_t)gy * Ww + gx) * 32 + u * 8);
            }
        }
#pragma unroll
        for (int k = 0; k < 2; ++k)
            if (dst[k] >= 0) *(short8*)&plds[dst[k]] = v[k];
    }
    __syncthreads();

    f32x4 acc[4][4];
#pragma unroll
    for (int mi = 0; mi < 4; ++mi)
#pragma unroll
        for (int ni = 0; ni < 4; ++ni)
            acc[mi][ni] = (f32x4)0.f;

    int wslot = l4 ^ ((l15 >> 1) & 3);
    for (int t = 0; t < 9; ++t) {
        if (t < 8) wstage(t + 1, (t + 1) & 1);
        int ky = t / 3, kx = t % 3;
        const ushort* wbase = wlds[t & 1];
        short8 a[4], bv[4];
#pragma unroll
        for (int mi = 0; mi < 4; ++mi) {
            int row = wM * 64 + mi * 16 + l15;
            a[mi] = *(const short8*)&wbase[row * 32 + wslot * 8];
        }
#pragma unroll
        for (int ni = 0; ni < 4; ++ni) {
            int ipx = (wN * 4 + ni + ky) * 18 + l15 + kx;
            bv[ni] = *(const short8*)&plds[ipx * 32
                    + ((l4 ^ ((ipx >> 1) & 3)) * 8)];
        }
#pragma unroll
        for (int mi = 0; mi < 4; ++mi)
#pragma unroll
            for (int ni = 0; ni < 4; ++ni)
                acc[mi][ni] = __builtin_amdgcn_mfma_f32_16x16x32_bf16(
                    a[mi], bv[ni], acc[mi][ni], 0, 0, 0);
        __syncthreads();
    }

    size_t ob = (size_t)b * OUTC * HW + (size_t)25 * HW;
    size_t pb = (size_t)b * HW;
#pragma unroll
    for (int mi = 0; mi < 4; ++mi)
#pragma unroll
        for (int ni = 0; ni < 4; ++ni) {
            int gy = y0 + wN * 4 + ni, gx = x0 + l15;
            int oc_b = wM * 64 + mi * 16 + l4 * 4;
            short4v hv;
#pragma unroll
            for (int r = 0; r < 4; ++r) {
                float v = fmaxf(acc[mi][ni][r] + b0[oc_b + r], 0.f);
                outp[ob + (size_t)(oc_b + r) * HW + (size_t)gy * Ww + gx] = v;
                hv[r] = (short)f2bf(v);
            }
            *(short4v*)&sspk[(pb + (size_t)gy * Ww + gx) * 256 + oc_b] = hv;
        }
}

// ============ kconv2n: 256->128 conv via MFMA, 16x8 tile ==================
#define NPX2 180
#define WGRP 12288   // ushorts per 24 KB weight group (3 taps x 128 x 32)
__global__ __launch_bounds__(256, 2) void kconv2n(const ushort* __restrict__ sspk,
                                                  const ushort* __restrict__ wpk,
                                                  const float* __restrict__ b1,
                                                  float* __restrict__ outp) {
    __shared__ ushort wlds[2][WGRP];       // 2 x 24 KB
    __shared__ ushort plds[2][NPX2 * 32];  // 2 x 11.52 KB
    int tid = threadIdx.x;
    int lane = tid & 63, wid = tid >> 6;
    int wM = wid >> 1, wN = wid & 1;
    int l15 = lane & 15, l4 = lane >> 4;
    int x0 = blockIdx.x * 16, y0 = blockIdx.y * 8, b = blockIdx.z;

    f32x4 acc[4][4];
#pragma unroll
    for (int mi = 0; mi < 4; ++mi)
#pragma unroll
        for (int ni = 0; ni < 4; ++ni)
            acc[mi][ni] = (f32x4)0.f;

    // pixel staging: 720 16B-units per chunk (180 px x 4 units), 3 tasks/thr
    size_t t_src[3];
    int t_dst[3];
    bool t_ok[3];
#pragma unroll
    for (int k = 0; k < 3; ++k) {
        int task = tid + k * 256;
        t_ok[k] = false; t_src[k] = 0; t_dst[k] = -1;
        if (task < 720) {
            int px = task >> 2, u = task & 3;
            int iy = px / 18, ix = px % 18;
            int gy = y0 + iy - 1, gx = x0 + ix - 1;
            t_dst[k] = px * 32 + (u ^ ((px >> 1) & 3)) * 8;
            if (gy >= 0 && gy < Hh && gx >= 0 && gx < Ww) {
                t_ok[k] = true;
                t_src[k] = ((size_t)b * HW + (size_t)gy * Ww + gx) * 256 + u * 8;
            }
        }
    }

    auto stage_load = [&](int c, short8* v) {
#pragma unroll
        for (int k = 0; k < 3; ++k) {
            v[k] = (short8)0;
            if (t_ok[k])
                v[k] = *(const short8*)(sspk + t_src[k] + c * 32);
        }
    };
    auto stage_write = [&](int nbuf, short8* v) {
#pragma unroll
        for (int k = 0; k < 3; ++k)
            if (t_dst[k] >= 0)
                *(short8*)&plds[nbuf][t_dst[k]] = v[k];
    };

    // cooperative weight DMA: group gi (24 KB) -> wlds[buf]; 6 x 1KB per wave
    auto wstage = [&](int gi, int buf) {
        const ushort* src = wpk + (size_t)gi * WGRP + wid * 3072 + lane * 8;
        ushort* dst = &wlds[buf][wid * 3072];
#pragma unroll
        for (int i = 0; i < 6; ++i)
            __builtin_amdgcn_global_load_lds((gu32*)(src + i * 512),
                                             (lu32*)(dst + i * 512), 16, 0, 0);
    };

    int wslot = l4 ^ ((l15 >> 1) & 3);
    auto compute = [&](int wb, int pb_, int ky) {
        const ushort* wbase = wlds[wb];
        const ushort* lbase = plds[pb_];
#pragma unroll
        for (int kx = 0; kx < 3; ++kx) {
            short8 a[4], bv[4];
#pragma unroll
            for (int mi = 0; mi < 4; ++mi) {
                int row = wM * 64 + mi * 16 + l15;
                a[mi] = *(const short8*)&wbase[(kx * 128 + row) * 32 + wslot * 8];
            }
#pragma unroll
            for (int ni = 0; ni < 4; ++ni) {
                int oy = wN * 4 + ni;
                int ipx = (oy + ky) * 18 + l15 + kx;
                bv[ni] = *(const short8*)&lbase[ipx * 32
                        + ((l4 ^ ((ipx >> 1) & 3)) * 8)];
            }
#pragma unroll
            for (int mi = 0; mi < 4; ++mi)
#pragma unroll
                for (int ni = 0; ni < 4; ++ni)
                    acc[mi][ni] = __builtin_amdgcn_mfma_f32_16x16x32_bf16(
                        a[mi], bv[ni], acc[mi][ni], 0, 0, 0);
        }
    };

    // prologue: weights group 0 + pixel chunk 0
    wstage(0, 0);
    {
        short8 sv[3];
        stage_load(0, sv);
        stage_write(0, sv);
    }
    __syncthreads();

    for (int c = 0; c < 8; ++c) {
        int gi = c * 3;
        short8 nv[3];
        // g = 0
        wstage(gi + 1, (gi + 1) & 1);
        if (c < 7) stage_load(c + 1, nv);
        compute(gi & 1, c & 1, 0);
        __syncthreads();
        // g = 1
        wstage(gi + 2, (gi + 2) & 1);
        compute((gi + 1) & 1, c & 1, 1);
        __syncthreads();
        // g = 2
        if (gi + 3 < 24) wstage(gi + 3, (gi + 3) & 1);
        if (c < 7) stage_write((c + 1) & 1, nv);
        compute((gi + 2) & 1, c & 1, 2);
        __syncthreads();
    }

    size_t ob = (size_t)b * OUTC * HW + (size_t)281 * HW;
#pragma unroll
    for (int mi = 0; mi < 4; ++mi)
#pragma unroll
        for (int ni = 0; ni < 4; ++ni) {
            int gy = y0 + wN * 4 + ni, gx = x0 + l15;
#pragma unroll
            for (int r = 0; r < 4; ++r) {
                int oc = wM * 64 + mi * 16 + l4 * 4 + r;
                float v = acc[mi][ni][r] + b1[oc];
                outp[ob + (size_t)oc * HW + (size_t)gy * Ww + gx] = fmaxf(v, 0.f);
            }
        }
}

extern "C" void kernel_launch(void* const* d_in, const int* in_sizes, int n_in,
                              void* d_out, int out_size, void* d_ws, size_t ws_size,
                              hipStream_t stream) {
    const float* feat = (const float*)d_in[0];
    const float* w0   = (const float*)d_in[1];
    const float* b0   = (const float*)d_in[2];
    const float* w1   = (const float*)d_in[3];
    const float* b1   = (const float*)d_in[4];
    float* out = (float*)d_out;

    // ws: wpk0 (147456) | wpk1 (589824) | sspk (37748736) | fnorm (75497472)
    //     | sspk0 (4718592)
    ushort* wpk0  = (ushort*)d_ws;
    ushort* wpk1  = (ushort*)((char*)d_ws + 147456);
    ushort* sspk  = (ushort*)((char*)d_ws + 147456 + 589824);
    ushort* fnorm = (ushort*)((char*)d_ws + 147456 + 589824 + 37748736);
    ushort* sspk0 = (ushort*)((char*)d_ws + 147456 + 589824 + 37748736
                              + 75497472);

    hipLaunchKernelGGL(kwpack0, dim3(288),  dim3(256), 0, stream, w0, wpk0);
    hipLaunchKernelGGL(kwpack1, dim3(1152), dim3(256), 0, stream, w1, wpk1);
    hipLaunchKernelGGL(kpack,   dim3(HW / PKPX, NB), dim3(256), 0, stream, feat, fnorm);
    hipLaunchKernelGGL(kss4,    dim3(12, 12, NB), dim3(256), 0, stream, fnorm, out, sspk0);
    hipLaunchKernelGGL(kconv1m, dim3(6, 12, NB), dim3(512), 0, stream, sspk0, wpk0, b0, out, sspk);
    hipLaunchKernelGGL(kconv2n, dim3(6, 12, NB), dim3(256), 0, stream, sspk, wpk1, b1, out);
}

// Round 4
// 206.983 us; speedup vs baseline: 1.7096x; 1.0133x over previous
//
#include <hip/hip_runtime.h>

#define FEAT_C 512
#define Hh 96
#define Ww 96
#define HW (Hh*Ww)
#define NB 8
#define OUTC 409

typedef __attribute__((ext_vector_type(8))) short short8;
typedef __attribute__((ext_vector_type(4))) short short4v;
typedef __attribute__((ext_vector_type(4))) float f32x4;
typedef __fp16 h2 __attribute__((ext_vector_type(2)));
typedef __fp16 h8 __attribute__((ext_vector_type(8)));

typedef __attribute__((address_space(1))) const unsigned int gu32;
typedef __attribute__((address_space(3))) unsigned int lu32;

__device__ inline ushort f2bf(float x) {
    unsigned u = __float_as_uint(x);
    u += 0x7fffu + ((u >> 16) & 1u);
    return (ushort)(u >> 16);
}

#if __has_builtin(__builtin_amdgcn_fdot2)
__device__ inline float FDOT2(h2 a, h2 b, float c) {
    return __builtin_amdgcn_fdot2(a, b, c, false);
}
#else
__device__ inline float FDOT2(h2 a, h2 b, float c) {
    return c + (float)a[0] * (float)b[0] + (float)a[1] * (float)b[1];
}
#endif

__device__ inline h2 pair(h8 v, int i) {
    switch (i) {
        case 0: return __builtin_shufflevector(v, v, 0, 1);
        case 1: return __builtin_shufflevector(v, v, 2, 3);
        case 2: return __builtin_shufflevector(v, v, 4, 5);
        default: return __builtin_shufflevector(v, v, 6, 7);
    }
}

// ============ kpack: normalize + transpose feature ========================
#define PKPX 32
__global__ __launch_bounds__(256) void kpack(const float* __restrict__ f,
                                             ushort* __restrict__ fnorm) {
    __shared__ ushort tr[PKPX * 512];      // 32 KB
    __shared__ float ssqp[8][PKPX];
    __shared__ float sinvs[PKPX];
    int tid = threadIdx.x;
    int g = tid >> 5, pl = tid & 31;
    int b = blockIdx.y;
    int p0 = blockIdx.x * PKPX;
    const float* fb = f + (size_t)b * FEAT_C * HW + p0 + pl;

    float ssq = 0.f;
#pragma unroll
    for (int q = 0; q < 8; ++q) {
        int u = g * 8 + q;
        float v[8];
#pragma unroll
        for (int j = 0; j < 8; ++j)
            v[j] = fb[(size_t)(u * 8 + j) * HW];
        h2 a0 = __builtin_amdgcn_cvt_pkrtz(v[0], v[1]);
        h2 a1 = __builtin_amdgcn_cvt_pkrtz(v[2], v[3]);
        h2 a2 = __builtin_amdgcn_cvt_pkrtz(v[4], v[5]);
        h2 a3 = __builtin_amdgcn_cvt_pkrtz(v[6], v[7]);
        ssq = FDOT2(a0, a0, ssq); ssq = FDOT2(a1, a1, ssq);
        ssq = FDOT2(a2, a2, ssq); ssq = FDOT2(a3, a3, ssq);
        h8 hv;
        hv[0] = a0[0]; hv[1] = a0[1]; hv[2] = a1[0]; hv[3] = a1[1];
        hv[4] = a2[0]; hv[5] = a2[1]; hv[6] = a3[0]; hv[7] = a3[1];
        int up = u ^ (pl & 7);
        *(h8*)&tr[pl * 512 + up * 8] = hv;
    }
    ssqp[g][pl] = ssq;
    __syncthreads();
    if (tid < PKPX) {
        float s = 0.f;
#pragma unroll
        for (int gg = 0; gg < 8; ++gg) s += ssqp[gg][tid];
        sinvs[tid] = 1.0f / fmaxf(sqrtf(s), 1e-12f);
    }
    __syncthreads();

    size_t ob = ((size_t)b * HW + p0) * 512;
#pragma unroll
    for (int i = 0; i < 8; ++i) {
        int t = tid + i * 256;
        int r = t >> 6, k = t & 63;
        h8 hv = *(const h8*)&tr[r * 512 + ((k ^ (r & 7)) * 8)];
        float s = sinvs[r];
        h2 o0 = __builtin_amdgcn_cvt_pkrtz((float)hv[0] * s, (float)hv[1] * s);
        h2 o1 = __builtin_amdgcn_cvt_pkrtz((float)hv[2] * s, (float)hv[3] * s);
        h2 o2 = __builtin_amdgcn_cvt_pkrtz((float)hv[4] * s, (float)hv[5] * s);
        h2 o3 = __builtin_amdgcn_cvt_pkrtz((float)hv[6] * s, (float)hv[7] * s);
        h8 ov;
        ov[0] = o0[0]; ov[1] = o0[1]; ov[2] = o1[0]; ov[3] = o1[1];
        ov[4] = o2[0]; ov[5] = o2[1]; ov[6] = o3[0]; ov[7] = o3[1];
        *(h8*)&fnorm[ob + (size_t)r * 512 + k * 8] = ov;
    }
}

// ============ kss4: self-similarity, 16x8 tile, vertical px-pairs =========
// grid (6,12,NB); 256 thr = 4 waves. Wave w owns tile rows {2w, 2w+1}.
// lane: q = lane&15 = x-col, s = lane>>4 = 8-ch slab. Each thread computes
// BOTH pixels of its column's row-pair: their 5x5 windows union to a 5x6
// window -> 30 shared LDS reads (vs 2x26). Halo tile 20x12 px, slot-
// swizzled with (px>>1)&3 so the stride-1 q-lanes are 2-way worst (free).
#define SS_NPX 240
__global__ __launch_bounds__(256) void kss4(const ushort* __restrict__ fnorm,
                                            float* __restrict__ out,
                                            ushort* __restrict__ sspk0) {
    __shared__ ushort tile[2][SS_NPX * 32];   // 2 x 15.36 KB
    int tid = threadIdx.x;
    int w = tid >> 6, lane = tid & 63;
    int s = lane >> 4, q = lane & 15;
    int x0 = blockIdx.x * 16, y0 = blockIdx.y * 8, b = blockIdx.z;

    // staging: 960 16B-units (240 px x 4), 4 tasks/thread, swizzled dst
    size_t t_src[4];
    int t_dst[4];
    bool t_ok[4];
#pragma unroll
    for (int k = 0; k < 4; ++k) {
        int task = tid + k * 256;
        t_ok[k] = false; t_src[k] = 0; t_dst[k] = -1;
        if (task < 960) {
            int px = task >> 2, u = task & 3;
            int hr = px / 20, hc = px % 20;
            int gy = y0 + hr - 2, gx = x0 + hc - 2;
            t_dst[k] = px * 32 + ((u ^ ((px >> 1) & 3)) * 8);
            if (gy >= 0 && gy < Hh && gx >= 0 && gx < Ww) {
                t_ok[k] = true;
                t_src[k] = ((size_t)b * HW + (size_t)gy * Ww + gx) * 512 + u * 8;
            }
        }
    }

    float acc0[25], acc1[25];
#pragma unroll
    for (int o = 0; o < 25; ++o) { acc0[o] = 0.f; acc1[o] = 0.f; }

    auto stage = [&](int chunk, int nbuf) {
        short8 v[4];
#pragma unroll
        for (int k = 0; k < 4; ++k) {
            v[k] = (short8)0;
            if (t_ok[k]) v[k] = *(const short8*)(fnorm + t_src[k] + chunk * 32);
        }
#pragma unroll
        for (int k = 0; k < 4; ++k)
            if (t_dst[k] >= 0)
                *(short8*)&tile[nbuf][t_dst[k]] = v[k];
    };

    auto compute = [&](int kb) {
        const ushort* tb = tile[kb];
        auto rd = [&](int px) -> h8 {
            return *(const h8*)&tb[px * 32 + ((s ^ ((px >> 1) & 3)) * 8)];
        };
        int pc0 = (2 * w + 2) * 20 + q + 2;
        h8 c0 = rd(pc0);
        h8 c1 = rd(pc0 + 20);
#pragma unroll
        for (int dxc = 0; dxc < 5; ++dxc) {
#pragma unroll
            for (int dyr = 0; dyr < 6; ++dyr) {
                int pn = (2 * w + dyr) * 20 + q + dxc;
                h8 nv = rd(pn);
                if (dyr < 5) {
                    float a = acc0[dxc * 5 + dyr];
                    a = FDOT2(pair(nv, 0), pair(c0, 0), a);
                    a = FDOT2(pair(nv, 1), pair(c0, 1), a);
                    a = FDOT2(pair(nv, 2), pair(c0, 2), a);
                    a = FDOT2(pair(nv, 3), pair(c0, 3), a);
                    acc0[dxc * 5 + dyr] = a;
                }
                if (dyr > 0) {
                    float a = acc1[dxc * 5 + dyr - 1];
                    a = FDOT2(pair(nv, 0), pair(c1, 0), a);
                    a = FDOT2(pair(nv, 1), pair(c1, 1), a);
                    a = FDOT2(pair(nv, 2), pair(c1, 2), a);
                    a = FDOT2(pair(nv, 3), pair(c1, 3), a);
                    acc1[dxc * 5 + dyr - 1] = a;
                }
            }
        }
    };

    stage(0, 0);
    __syncthreads();
    for (int c = 0; c < 16; ++c) {
        if (c < 15) stage(c + 1, (c + 1) & 1);
        compute(c & 1);
        __syncthreads();
    }

    // reduce across the 4 slabs (lane quarters)
#pragma unroll
    for (int o = 0; o < 25; ++o) {
        float v0 = acc0[o];
        v0 += __shfl_xor(v0, 16);
        v0 += __shfl_xor(v0, 32);
        acc0[o] = v0;
        float v1 = acc1[o];
        v1 += __shfl_xor(v1, 16);
        v1 += __shfl_xor(v1, 32);
        acc1[o] = v1;
    }
    if (s == 0) {
        int gy0 = y0 + 2 * w, gx = x0 + q;
        size_t pix0 = (size_t)b * HW + (size_t)gy0 * Ww + gx;
        size_t ob0 = (size_t)b * OUTC * HW + (size_t)gy0 * Ww + gx;
#pragma unroll
        for (int o = 0; o < 25; ++o) {
            out[ob0 + (size_t)o * HW] = acc0[o];
            out[ob0 + (size_t)o * HW + Ww] = acc1[o];
        }
        ushort pk0[32], pk1[32];
#pragma unroll
        for (int o = 0; o < 25; ++o) { pk0[o] = f2bf(acc0[o]); pk1[o] = f2bf(acc1[o]); }
#pragma unroll
        for (int o = 25; o < 32; ++o) { pk0[o] = 0; pk1[o] = 0; }
#pragma unroll
        for (int u = 0; u < 4; ++u) {
            *(short8*)&sspk0[pix0 * 32 + u * 8] = *(short8*)&pk0[u * 8];
            *(short8*)&sspk0[(pix0 + Ww) * 32 + u * 8] = *(short8*)&pk1[u * 8];
        }
    }
}

// ============ weight repacks ==============================================
// w0 [256][25][3][3] f32 -> wpk0 [9 t][256 oc][4 slot][8] bf16 with the
// ds_read bank swizzle BAKED IN: slot s holds ic-unit u = s ^ ((oc>>1)&3)
// (global_load_lds writes LDS linearly -> swizzle lives in global layout).
__global__ __launch_bounds__(256) void kwpack0(const float* __restrict__ w0,
                                               ushort* __restrict__ wpk0) {
    int i = blockIdx.x * 256 + threadIdx.x;
    if (i >= 9 * 256 * 32) return;
    int t = i >> 13, oc = (i >> 5) & 255;
    int s = (i >> 3) & 3, ii = i & 7;
    int u = s ^ ((oc >> 1) & 3);
    int ic = u * 8 + ii;
    wpk0[i] = (ic < 25) ? f2bf(w0[(size_t)oc * 225 + ic * 9 + t]) : (ushort)0;
}

// w1 [128][256][3][3] f32 -> wpk1 [8 chunk][3 ky][3 kx][128 oc][4 slot][8]
// bf16, same baked swizzle u = s ^ ((oc>>1)&3).
__global__ __launch_bounds__(256) void kwpack1(const float* __restrict__ w1,
                                               ushort* __restrict__ wpk1) {
    int i = blockIdx.x * 256 + threadIdx.x;
    if (i >= 8 * 9 * 128 * 32) return;
    int ct = i >> 12;                 // (c*9 + t), 128*32 = 4096
    int c = ct / 9, t = ct % 9;
    int oc = (i >> 5) & 127;
    int s = (i >> 3) & 3, ii = i & 7;
    int u = s ^ ((oc >> 1) & 3);
    int ic = c * 32 + u * 8 + ii;
    wpk1[i] = f2bf(w1[((size_t)oc * 256 + ic) * 9 + t]);
}

// ============ kconv1m: 25->256 conv via MFMA, 16x8 tile, 512 thr ==========
#define C1NPX 180
__global__ __launch_bounds__(512, 2) void kconv1m(const ushort* __restrict__ sspk0,
                                                  const ushort* __restrict__ wpk0,
                                                  const float* __restrict__ b0,
                                                  float* __restrict__ outp,
                                                  ushort* __restrict__ sspk) {
    __shared__ ushort wlds[2][8192];      // 2 x 16 KB (one tap: 256 oc x 32)
    __shared__ ushort plds[C1NPX * 32];   // 11.52 KB
    int tid = threadIdx.x;
    int lane = tid & 63, wid = tid >> 6;
    int wM = wid >> 1, wN = wid & 1;
    int l15 = lane & 15, l4 = lane >> 4;
    int x0 = blockIdx.x * 16, y0 = blockIdx.y * 8, b = blockIdx.z;

    // weight DMA: tap t (16 KB = 1024 16B-units) -> wlds[buf]; 2 units/thread
    auto wstage = [&](int t, int buf) {
        const ushort* src = wpk0 + (size_t)t * 8192 + wid * 1024 + lane * 8;
        ushort* dst = &wlds[buf][wid * 1024];
#pragma unroll
        for (int i = 0; i < 2; ++i)
            __builtin_amdgcn_global_load_lds((gu32*)(src + i * 512),
                                             (lu32*)(dst + i * 512), 16, 0, 0);
    };

    wstage(0, 0);

    // pixel staging: 720 16B-units (180 px x 4), swizzled LDS dst
    {
        short8 v[2]; int dst[2];
#pragma unroll
        for (int k = 0; k < 2; ++k) {
            int task = tid + k * 512;
            v[k] = (short8)0; dst[k] = -1;
            if (task < 720) {
                int px = task >> 2, u = task & 3;
                int iy = px / 18, ix = px % 18;
                int gy = y0 + iy - 1, gx = x0 + ix - 1;
                dst[k] = px * 32 + (u ^ ((px >> 1) & 3)) * 8;
                if (gy >= 0 && gy < Hh && gx >= 0 && gx < Ww)
                    v[k] = *(const short8*)(sspk0 +
                            ((size_t)b * HW + (size_t)gy * Ww + gx) * 32 + u * 8);
            }
        }
#pragma unroll
        for (int k = 0; k < 2; ++k)
            if (dst[k] >= 0) *(short8*)&plds[dst[k]] = v[k];
    }
    __syncthreads();

    f32x4 acc[4][4];
#pragma unroll
    for (int mi = 0; mi < 4; ++mi)
#pragma unroll
        for (int ni = 0; ni < 4; ++ni)
            acc[mi][ni] = (f32x4)0.f;

    int wslot = l4 ^ ((l15 >> 1) & 3);
    for (int t = 0; t < 9; ++t) {
        if (t < 8) wstage(t + 1, (t + 1) & 1);
        int ky = t / 3, kx = t % 3;
        const ushort* wbase = wlds[t & 1];
        short8 a[4], bv[4];
#pragma unroll
        for (int mi = 0; mi < 4; ++mi) {
            int row = wM * 64 + mi * 16 + l15;
            a[mi] = *(const short8*)&wbase[row * 32 + wslot * 8];
        }
#pragma unroll
        for (int ni = 0; ni < 4; ++ni) {
            int ipx = (wN * 4 + ni + ky) * 18 + l15 + kx;
            bv[ni] = *(const short8*)&plds[ipx * 32
                    + ((l4 ^ ((ipx >> 1) & 3)) * 8)];
        }
#pragma unroll
        for (int mi = 0; mi < 4; ++mi)
#pragma unroll
            for (int ni = 0; ni < 4; ++ni)
                acc[mi][ni] = __builtin_amdgcn_mfma_f32_16x16x32_bf16(
                    a[mi], bv[ni], acc[mi][ni], 0, 0, 0);
        __syncthreads();
    }

    size_t ob = (size_t)b * OUTC * HW + (size_t)25 * HW;
    size_t pb = (size_t)b * HW;
#pragma unroll
    for (int mi = 0; mi < 4; ++mi)
#pragma unroll
        for (int ni = 0; ni < 4; ++ni) {
            int gy = y0 + wN * 4 + ni, gx = x0 + l15;
            int oc_b = wM * 64 + mi * 16 + l4 * 4;
            short4v hv;
#pragma unroll
            for (int r = 0; r < 4; ++r) {
                float v = fmaxf(acc[mi][ni][r] + b0[oc_b + r], 0.f);
                outp[ob + (size_t)(oc_b + r) * HW + (size_t)gy * Ww + gx] = v;
                hv[r] = (short)f2bf(v);
            }
            *(short4v*)&sspk[(pb + (size_t)gy * Ww + gx) * 256 + oc_b] = hv;
        }
}

// ============ kconv2n: 256->128 conv via MFMA, 16x8 tile ==================
#define NPX2 180
#define WGRP 12288   // ushorts per 24 KB weight group (3 taps x 128 x 32)
__global__ __launch_bounds__(256, 2) void kconv2n(const ushort* __restrict__ sspk,
                                                  const ushort* __restrict__ wpk,
                                                  const float* __restrict__ b1,
                                                  float* __restrict__ outp) {
    __shared__ ushort wlds[2][WGRP];       // 2 x 24 KB
    __shared__ ushort plds[2][NPX2 * 32];  // 2 x 11.52 KB
    int tid = threadIdx.x;
    int lane = tid & 63, wid = tid >> 6;
    int wM = wid >> 1, wN = wid & 1;
    int l15 = lane & 15, l4 = lane >> 4;
    int x0 = blockIdx.x * 16, y0 = blockIdx.y * 8, b = blockIdx.z;

    f32x4 acc[4][4];
#pragma unroll
    for (int mi = 0; mi < 4; ++mi)
#pragma unroll
        for (int ni = 0; ni < 4; ++ni)
            acc[mi][ni] = (f32x4)0.f;

    // pixel staging: 720 16B-units per chunk (180 px x 4 units), 3 tasks/thr
    size_t t_src[3];
    int t_dst[3];
    bool t_ok[3];
#pragma unroll
    for (int k = 0; k < 3; ++k) {
        int task = tid + k * 256;
        t_ok[k] = false; t_src[k] = 0; t_dst[k] = -1;
        if (task < 720) {
            int px = task >> 2, u = task & 3;
            int iy = px / 18, ix = px % 18;
            int gy = y0 + iy - 1, gx = x0 + ix - 1;
            t_dst[k] = px * 32 + (u ^ ((px >> 1) & 3)) * 8;
            if (gy >= 0 && gy < Hh && gx >= 0 && gx < Ww) {
                t_ok[k] = true;
                t_src[k] = ((size_t)b * HW + (size_t)gy * Ww + gx) * 256 + u * 8;
            }
        }
    }

    auto stage_load = [&](int c, short8* v) {
#pragma unroll
        for (int k = 0; k < 3; ++k) {
            v[k] = (short8)0;
            if (t_ok[k])
                v[k] = *(const short8*)(sspk + t_src[k] + c * 32);
        }
    };
    auto stage_write = [&](int nbuf, short8* v) {
#pragma unroll
        for (int k = 0; k < 3; ++k)
            if (t_dst[k] >= 0)
                *(short8*)&plds[nbuf][t_dst[k]] = v[k];
    };

    // cooperative weight DMA: group gi (24 KB) -> wlds[buf]; 6 x 1KB per wave
    auto wstage = [&](int gi, int buf) {
        const ushort* src = wpk + (size_t)gi * WGRP + wid * 3072 + lane * 8;
        ushort* dst = &wlds[buf][wid * 3072];
#pragma unroll
        for (int i = 0; i < 6; ++i)
            __builtin_amdgcn_global_load_lds((gu32*)(src + i * 512),
                                             (lu32*)(dst + i * 512), 16, 0, 0);
    };

    int wslot = l4 ^ ((l15 >> 1) & 3);
    auto compute = [&](int wb, int pb_, int ky) {
        const ushort* wbase = wlds[wb];
        const ushort* lbase = plds[pb_];
#pragma unroll
        for (int kx = 0; kx < 3; ++kx) {
            short8 a[4], bv[4];
#pragma unroll
            for (int mi = 0; mi < 4; ++mi) {
                int row = wM * 64 + mi * 16 + l15;
                a[mi] = *(const short8*)&wbase[(kx * 128 + row) * 32 + wslot * 8];
            }
#pragma unroll
            for (int ni = 0; ni < 4; ++ni) {
                int oy = wN * 4 + ni;
                int ipx = (oy + ky) * 18 + l15 + kx;
                bv[ni] = *(const short8*)&lbase[ipx * 32
                        + ((l4 ^ ((ipx >> 1) & 3)) * 8)];
            }
#pragma unroll
            for (int mi = 0; mi < 4; ++mi)
#pragma unroll
                for (int ni = 0; ni < 4; ++ni)
                    acc[mi][ni] = __builtin_amdgcn_mfma_f32_16x16x32_bf16(
                        a[mi], bv[ni], acc[mi][ni], 0, 0, 0);
        }
    };

    // prologue: weights group 0 + pixel chunk 0
    wstage(0, 0);
    {
        short8 sv[3];
        stage_load(0, sv);
        stage_write(0, sv);
    }
    __syncthreads();

    for (int c = 0; c < 8; ++c) {
        int gi = c * 3;
        short8 nv[3];
        // g = 0
        wstage(gi + 1, (gi + 1) & 1);
        if (c < 7) stage_load(c + 1, nv);
        compute(gi & 1, c & 1, 0);
        __syncthreads();
        // g = 1
        wstage(gi + 2, (gi + 2) & 1);
        compute((gi + 1) & 1, c & 1, 1);
        __syncthreads();
        // g = 2
        if (gi + 3 < 24) wstage(gi + 3, (gi + 3) & 1);
        if (c < 7) stage_write((c + 1) & 1, nv);
        compute((gi + 2) & 1, c & 1, 2);
        __syncthreads();
    }

    size_t ob = (size_t)b * OUTC * HW + (size_t)281 * HW;
#pragma unroll
    for (int mi = 0; mi < 4; ++mi)
#pragma unroll
        for (int ni = 0; ni < 4; ++ni) {
            int gy = y0 + wN * 4 + ni, gx = x0 + l15;
#pragma unroll
            for (int r = 0; r < 4; ++r) {
                int oc = wM * 64 + mi * 16 + l4 * 4 + r;
                float v = acc[mi][ni][r] + b1[oc];
                outp[ob + (size_t)oc * HW + (size_t)gy * Ww + gx] = fmaxf(v, 0.f);
            }
        }
}

extern "C" void kernel_launch(void* const* d_in, const int* in_sizes, int n_in,
                              void* d_out, int out_size, void* d_ws, size_t ws_size,
                              hipStream_t stream) {
    const float* feat = (const float*)d_in[0];
    const float* w0   = (const float*)d_in[1];
    const float* b0   = (const float*)d_in[2];
    const float* w1   = (const float*)d_in[3];
    const float* b1   = (const float*)d_in[4];
    float* out = (float*)d_out;

    // ws: wpk0 (147456) | wpk1 (589824) | sspk (37748736) | fnorm (75497472)
    //     | sspk0 (4718592)
    ushort* wpk0  = (ushort*)d_ws;
    ushort* wpk1  = (ushort*)((char*)d_ws + 147456);
    ushort* sspk  = (ushort*)((char*)d_ws + 147456 + 589824);
    ushort* fnorm = (ushort*)((char*)d_ws + 147456 + 589824 + 37748736);
    ushort* sspk0 = (ushort*)((char*)d_ws + 147456 + 589824 + 37748736
                              + 75497472);

    hipLaunchKernelGGL(kwpack0, dim3(288),  dim3(256), 0, stream, w0, wpk0);
    hipLaunchKernelGGL(kwpack1, dim3(1152), dim3(256), 0, stream, w1, wpk1);
    hipLaunchKernelGGL(kpack,   dim3(HW / PKPX, NB), dim3(256), 0, stream, feat, fnorm);
    hipLaunchKernelGGL(kss4,    dim3(6, 12, NB), dim3(256), 0, stream, fnorm, out, sspk0);
    hipLaunchKernelGGL(kconv1m, dim3(6, 12, NB), dim3(512), 0, stream, sspk0, wpk0, b0, out, sspk);
    hipLaunchKernelGGL(kconv2n, dim3(6, 12, NB), dim3(256), 0, stream, sspk, wpk1, b1, out);
}